// Round 7
// baseline (93.545 us; speedup 1.0000x reference)
//
#include <hip/hip_runtime.h>

#define S_PTS 4096  // sparse point count (fixed by problem)

// Branchless sorted top-3 insert using min/med3 for values.
// Invariant: b0 <= b1 <= b2. Strict '<' keeps earliest index on ties
// (matches jax.lax.top_k first-occurrence tie-breaking).
// Value updates (each uses only OLD values -> mutually independent):
//   b0' = min(b0, d)
//   b1' = med3(b0, b1, d)   [d<=b0 -> b0 | b0<d<=b1 -> d | d>b1 -> b1]
//   b2' = med3(b1, b2, d)   [d<=b1 -> b1 | b1<d<=b2 -> d | d>b2 -> b2]
__device__ __forceinline__ void insert3(float d, int s,
    float& b0, float& b1, float& b2, int& i0, int& i1, int& i2)
{
    const bool lt0 = d < b0, lt1 = d < b1, lt2 = d < b2;
    i2 = lt1 ? i1 : (lt2 ? s : i2);   // reads old i1
    i1 = lt0 ? i0 : (lt1 ? s : i1);   // reads old i0
    i0 = lt0 ? s : i0;
    const float nb0 = fminf(b0, d);
    const float nb1 = __builtin_amdgcn_fmed3f(b0, b1, d);
    const float nb2 = __builtin_amdgcn_fmed3f(b1, b2, d);
    b0 = nb0; b1 = nb1; b2 = nb2;
}

// Finalize one query: weights from direct-diff norm (matches reference),
// gather flow, write 3 channels. Identical math to the passing kernels.
__device__ __forceinline__ void finalize_query(
    const float4* __restrict__ spt, const float* __restrict__ fl,
    float* __restrict__ ob, int N, int n,
    float x0, float x1, float x2, int i0, int i1, int i2)
{
    const float4 p0 = spt[i0];
    const float4 p1 = spt[i1];
    const float4 p2 = spt[i2];

    float dx, dy, dz;
    dx = p0.x - x0; dy = p0.y - x1; dz = p0.z - x2;
    const float dist0 = fmaxf(sqrtf(dx * dx + dy * dy + dz * dz), 1e-10f);
    dx = p1.x - x0; dy = p1.y - x1; dz = p1.z - x2;
    const float dist1 = fmaxf(sqrtf(dx * dx + dy * dy + dz * dz), 1e-10f);
    dx = p2.x - x0; dy = p2.y - x1; dz = p2.z - x2;
    const float dist2 = fmaxf(sqrtf(dx * dx + dy * dy + dz * dz), 1e-10f);

    const float inv0 = 1.0f / dist0;
    const float inv1 = 1.0f / dist1;
    const float inv2 = 1.0f / dist2;
    const float wsum = (inv0 + inv1) + inv2;
    const float w0 = inv0 / wsum;
    const float w1 = inv1 / wsum;
    const float w2 = inv2 / wsum;

    #pragma unroll
    for (int c = 0; c < 3; ++c) {
        const float f0 = fl[c * S_PTS + i0];
        const float f1 = fl[c * S_PTS + i1];
        const float f2 = fl[c * S_PTS + i2];
        ob[c * N + n] = (w0 * f0 + w1 * f1) + w2 * f2;
    }
}

// 256 threads = 32 query-groups x 8 scanner lanes; each lane owns R=2 queries.
// 64 queries/block. LDS = 64 KB -> 2 blocks/CU (8 waves/CU).
__global__ __launch_bounds__(256, 2)
void upsample_flow_knn3(const float* __restrict__ xyz,         // [B,3,N]
                        const float* __restrict__ sparse_xyz,  // [B,3,S]
                        const float* __restrict__ sparse_flow, // [B,3,S]
                        float* __restrict__ out,               // [B,3,N]
                        int N, int blocks_per_batch)
{
    __shared__ float4 spt[S_PTS];  // (x, y, z, |s|^2)

    const int tid = threadIdx.x;
    const int b   = blockIdx.x / blocks_per_batch;
    const int qb  = blockIdx.x % blocks_per_batch;

    // ---- stage sparse points (+ precomputed squared norm) into LDS ----
    const float* sx = sparse_xyz + (size_t)b * 3 * S_PTS;
    for (int i = tid; i < S_PTS; i += 256) {
        const float px = sx[i];
        const float py = sx[S_PTS + i];
        const float pz = sx[2 * S_PTS + i];
        // match np: (px*px + py*py) + pz*pz, no FMA contraction
        const float sn = __fadd_rn(
            __fadd_rn(__fmul_rn(px, px), __fmul_rn(py, py)),
            __fmul_rn(pz, pz));
        spt[i] = make_float4(px, py, pz, sn);
    }
    __syncthreads();

    const int g = tid >> 3;   // query group within block (0..31)
    const int j = tid & 7;    // scanner lane within group (0..7)
    const int nA = qb * 64 + g;
    const int nB = nA + 32;

    const float* xq = xyz + (size_t)b * 3 * N;
    const float xA0 = xq[nA];
    const float xA1 = xq[N + nA];
    const float xA2 = xq[2 * N + nA];
    const float qnA = __fadd_rn(
        __fadd_rn(__fmul_rn(xA0, xA0), __fmul_rn(xA1, xA1)),
        __fmul_rn(xA2, xA2));
    const float xB0 = xq[nB];
    const float xB1 = xq[N + nB];
    const float xB2 = xq[2 * N + nB];
    const float qnB = __fadd_rn(
        __fadd_rn(__fmul_rn(xB0, xB0), __fmul_rn(xB1, xB1)),
        __fmul_rn(xB2, xB2));

    float a0 = 3.4e38f, a1 = 3.4e38f, a2 = 3.4e38f;
    int  ia0 = 0, ia1 = 0, ia2 = 0;
    float c0 = 3.4e38f, c1 = 3.4e38f, c2 = 3.4e38f;
    int  ib0 = 0, ib1 = 0, ib2 = 0;

    // ---- scan: lane j handles s = 8*i + j; one LDS read feeds 2 queries ----
    #pragma unroll 8
    for (int i = 0; i < S_PTS / 8; ++i) {
        const int s = (i << 3) | j;
        const float4 p = spt[s];

        // expanded-form d2, same op order as the passing kernels:
        // d2 = (qn - 2*dot) + sn,  dot = (x0*px + x1*py) + x2*pz
        const float dotA = __fadd_rn(
            __fadd_rn(__fmul_rn(xA0, p.x), __fmul_rn(xA1, p.y)),
            __fmul_rn(xA2, p.z));
        const float d2A = __fadd_rn(
            __fsub_rn(qnA, __fmul_rn(2.0f, dotA)), p.w);
        insert3(d2A, s, a0, a1, a2, ia0, ia1, ia2);

        const float dotB = __fadd_rn(
            __fadd_rn(__fmul_rn(xB0, p.x), __fmul_rn(xB1, p.y)),
            __fmul_rn(xB2, p.z));
        const float d2B = __fadd_rn(
            __fsub_rn(qnB, __fmul_rn(2.0f, dotB)), p.w);
        insert3(d2B, s, c0, c1, c2, ib0, ib1, ib2);
    }

    // ---- merge the 8 partial top-3s per query (butterfly within group) ----
    #pragma unroll
    for (int m = 1; m <= 4; m <<= 1) {
        const float ra0 = __shfl_xor(a0, m, 64);
        const float ra1 = __shfl_xor(a1, m, 64);
        const float ra2 = __shfl_xor(a2, m, 64);
        const int   ka0 = __shfl_xor(ia0, m, 64);
        const int   ka1 = __shfl_xor(ia1, m, 64);
        const int   ka2 = __shfl_xor(ia2, m, 64);
        insert3(ra0, ka0, a0, a1, a2, ia0, ia1, ia2);
        insert3(ra1, ka1, a0, a1, a2, ia0, ia1, ia2);
        insert3(ra2, ka2, a0, a1, a2, ia0, ia1, ia2);

        const float rb0 = __shfl_xor(c0, m, 64);
        const float rb1 = __shfl_xor(c1, m, 64);
        const float rb2 = __shfl_xor(c2, m, 64);
        const int   kb0 = __shfl_xor(ib0, m, 64);
        const int   kb1 = __shfl_xor(ib1, m, 64);
        const int   kb2 = __shfl_xor(ib2, m, 64);
        insert3(rb0, kb0, c0, c1, c2, ib0, ib1, ib2);
        insert3(rb1, kb1, c0, c1, c2, ib0, ib1, ib2);
        insert3(rb2, kb2, c0, c1, c2, ib0, ib1, ib2);
    }

    // ---- finalize both queries on lane j==0 ----
    if (j == 0) {
        const float* fl = sparse_flow + (size_t)b * 3 * S_PTS;
        float* ob = out + (size_t)b * 3 * N;
        if (nA < N)
            finalize_query(spt, fl, ob, N, nA, xA0, xA1, xA2, ia0, ia1, ia2);
        if (nB < N)
            finalize_query(spt, fl, ob, N, nB, xB0, xB1, xB2, ib0, ib1, ib2);
    }
}

extern "C" void kernel_launch(void* const* d_in, const int* in_sizes, int n_in,
                              void* d_out, int out_size, void* d_ws, size_t ws_size,
                              hipStream_t stream)
{
    const float* xyz         = (const float*)d_in[0];
    const float* sparse_xyz  = (const float*)d_in[1];
    const float* sparse_flow = (const float*)d_in[2];
    float* out = (float*)d_out;

    const int B = in_sizes[1] / (3 * S_PTS);      // 2
    const int N = in_sizes[0] / (3 * B);          // 16384
    const int blocks_per_batch = (N + 63) / 64;   // 256

    dim3 grid(B * blocks_per_batch);
    dim3 block(256);
    upsample_flow_knn3<<<grid, block, 0, stream>>>(
        xyz, sparse_xyz, sparse_flow, out, N, blocks_per_batch);
}

// Round 8
// 92.910 us; speedup vs baseline: 1.0068x; 1.0068x over previous
//
#include <hip/hip_runtime.h>

#define S_PTS 4096  // sparse point count (fixed by problem)

// Branchless sorted top-3 insert using min/med3 for values.
// Invariant: b0 <= b1 <= b2. Strict '<' keeps earliest index on ties
// (matches jax.lax.top_k first-occurrence tie-breaking).
// Value updates (each uses only OLD values -> mutually independent):
//   b0' = min(b0, d)
//   b1' = med3(b0, b1, d)   [d<=b0 -> b0 | b0<d<=b1 -> d | d>b1 -> b1]
//   b2' = med3(b1, b2, d)   [d<=b1 -> b1 | b1<d<=b2 -> d | d>b2 -> b2]
__device__ __forceinline__ void insert3(float d, int s,
    float& b0, float& b1, float& b2, int& i0, int& i1, int& i2)
{
    const bool lt0 = d < b0, lt1 = d < b1, lt2 = d < b2;
    i2 = lt1 ? i1 : (lt2 ? s : i2);   // reads old i1
    i1 = lt0 ? i0 : (lt1 ? s : i1);   // reads old i0
    i0 = lt0 ? s : i0;
    const float nb0 = fminf(b0, d);
    const float nb1 = __builtin_amdgcn_fmed3f(b0, b1, d);
    const float nb2 = __builtin_amdgcn_fmed3f(b1, b2, d);
    b0 = nb0; b1 = nb1; b2 = nb2;
}

// Finalize one query: weights from direct-diff norm (matches reference),
// gather flow, write 3 channels. Identical math to the passing kernels.
__device__ __forceinline__ void finalize_query(
    const float4* __restrict__ spt, const float* __restrict__ fl,
    float* __restrict__ ob, int N, int n,
    float x0, float x1, float x2, int i0, int i1, int i2)
{
    const float4 p0 = spt[i0];
    const float4 p1 = spt[i1];
    const float4 p2 = spt[i2];

    float dx, dy, dz;
    dx = p0.x - x0; dy = p0.y - x1; dz = p0.z - x2;
    const float dist0 = fmaxf(sqrtf(dx * dx + dy * dy + dz * dz), 1e-10f);
    dx = p1.x - x0; dy = p1.y - x1; dz = p1.z - x2;
    const float dist1 = fmaxf(sqrtf(dx * dx + dy * dy + dz * dz), 1e-10f);
    dx = p2.x - x0; dy = p2.y - x1; dz = p2.z - x2;
    const float dist2 = fmaxf(sqrtf(dx * dx + dy * dy + dz * dz), 1e-10f);

    const float inv0 = 1.0f / dist0;
    const float inv1 = 1.0f / dist1;
    const float inv2 = 1.0f / dist2;
    const float wsum = (inv0 + inv1) + inv2;
    const float w0 = inv0 / wsum;
    const float w1 = inv1 / wsum;
    const float w2 = inv2 / wsum;

    #pragma unroll
    for (int c = 0; c < 3; ++c) {
        const float f0 = fl[c * S_PTS + i0];
        const float f1 = fl[c * S_PTS + i1];
        const float f2 = fl[c * S_PTS + i2];
        ob[c * N + n] = (w0 * f0 + w1 * f1) + w2 * f2;
    }
}

// 256 threads = 32 query-groups x 8 scanner lanes; each lane owns R=2 queries.
// 64 queries/block. LDS = 64 KB -> 2 blocks/CU (8 waves/CU).
__global__ __launch_bounds__(256, 2)
void upsample_flow_knn3(const float* __restrict__ xyz,         // [B,3,N]
                        const float* __restrict__ sparse_xyz,  // [B,3,S]
                        const float* __restrict__ sparse_flow, // [B,3,S]
                        float* __restrict__ out,               // [B,3,N]
                        int N, int blocks_per_batch)
{
    __shared__ float4 spt[S_PTS];  // (x, y, z, |s|^2)

    const int tid = threadIdx.x;
    const int b   = blockIdx.x / blocks_per_batch;
    const int qb  = blockIdx.x % blocks_per_batch;

    // ---- stage sparse points (+ precomputed squared norm) into LDS ----
    const float* sx = sparse_xyz + (size_t)b * 3 * S_PTS;
    for (int i = tid; i < S_PTS; i += 256) {
        const float px = sx[i];
        const float py = sx[S_PTS + i];
        const float pz = sx[2 * S_PTS + i];
        // match np: (px*px + py*py) + pz*pz, no FMA contraction
        const float sn = __fadd_rn(
            __fadd_rn(__fmul_rn(px, px), __fmul_rn(py, py)),
            __fmul_rn(pz, pz));
        spt[i] = make_float4(px, py, pz, sn);
    }
    __syncthreads();

    const int g = tid >> 3;   // query group within block (0..31)
    const int j = tid & 7;    // scanner lane within group (0..7)
    const int nA = qb * 64 + g;
    const int nB = nA + 32;

    const float* xq = xyz + (size_t)b * 3 * N;
    const float xA0 = xq[nA];
    const float xA1 = xq[N + nA];
    const float xA2 = xq[2 * N + nA];
    const float qnA = __fadd_rn(
        __fadd_rn(__fmul_rn(xA0, xA0), __fmul_rn(xA1, xA1)),
        __fmul_rn(xA2, xA2));
    const float xB0 = xq[nB];
    const float xB1 = xq[N + nB];
    const float xB2 = xq[2 * N + nB];
    const float qnB = __fadd_rn(
        __fadd_rn(__fmul_rn(xB0, xB0), __fmul_rn(xB1, xB1)),
        __fmul_rn(xB2, xB2));

    float a0 = 3.4e38f, a1 = 3.4e38f, a2 = 3.4e38f;
    int  ia0 = 0, ia1 = 0, ia2 = 0;
    float c0 = 3.4e38f, c1 = 3.4e38f, c2 = 3.4e38f;
    int  ib0 = 0, ib1 = 0, ib2 = 0;

    // ---- scan: lane j handles s = 8*i + j; one LDS read feeds 2 queries ----
    #pragma unroll 8
    for (int i = 0; i < S_PTS / 8; ++i) {
        const int s = (i << 3) | j;
        const float4 p = spt[s];

        // expanded-form d2, same op order as the passing kernels:
        // d2 = (qn - 2*dot) + sn,  dot = (x0*px + x1*py) + x2*pz
        const float dotA = __fadd_rn(
            __fadd_rn(__fmul_rn(xA0, p.x), __fmul_rn(xA1, p.y)),
            __fmul_rn(xA2, p.z));
        const float d2A = __fadd_rn(
            __fsub_rn(qnA, __fmul_rn(2.0f, dotA)), p.w);
        insert3(d2A, s, a0, a1, a2, ia0, ia1, ia2);

        const float dotB = __fadd_rn(
            __fadd_rn(__fmul_rn(xB0, p.x), __fmul_rn(xB1, p.y)),
            __fmul_rn(xB2, p.z));
        const float d2B = __fadd_rn(
            __fsub_rn(qnB, __fmul_rn(2.0f, dotB)), p.w);
        insert3(d2B, s, c0, c1, c2, ib0, ib1, ib2);
    }

    // ---- merge the 8 partial top-3s per query (butterfly within group) ----
    #pragma unroll
    for (int m = 1; m <= 4; m <<= 1) {
        const float ra0 = __shfl_xor(a0, m, 64);
        const float ra1 = __shfl_xor(a1, m, 64);
        const float ra2 = __shfl_xor(a2, m, 64);
        const int   ka0 = __shfl_xor(ia0, m, 64);
        const int   ka1 = __shfl_xor(ia1, m, 64);
        const int   ka2 = __shfl_xor(ia2, m, 64);
        insert3(ra0, ka0, a0, a1, a2, ia0, ia1, ia2);
        insert3(ra1, ka1, a0, a1, a2, ia0, ia1, ia2);
        insert3(ra2, ka2, a0, a1, a2, ia0, ia1, ia2);

        const float rb0 = __shfl_xor(c0, m, 64);
        const float rb1 = __shfl_xor(c1, m, 64);
        const float rb2 = __shfl_xor(c2, m, 64);
        const int   kb0 = __shfl_xor(ib0, m, 64);
        const int   kb1 = __shfl_xor(ib1, m, 64);
        const int   kb2 = __shfl_xor(ib2, m, 64);
        insert3(rb0, kb0, c0, c1, c2, ib0, ib1, ib2);
        insert3(rb1, kb1, c0, c1, c2, ib0, ib1, ib2);
        insert3(rb2, kb2, c0, c1, c2, ib0, ib1, ib2);
    }

    // ---- finalize both queries on lane j==0 ----
    if (j == 0) {
        const float* fl = sparse_flow + (size_t)b * 3 * S_PTS;
        float* ob = out + (size_t)b * 3 * N;
        if (nA < N)
            finalize_query(spt, fl, ob, N, nA, xA0, xA1, xA2, ia0, ia1, ia2);
        if (nB < N)
            finalize_query(spt, fl, ob, N, nB, xB0, xB1, xB2, ib0, ib1, ib2);
    }
}

extern "C" void kernel_launch(void* const* d_in, const int* in_sizes, int n_in,
                              void* d_out, int out_size, void* d_ws, size_t ws_size,
                              hipStream_t stream)
{
    const float* xyz         = (const float*)d_in[0];
    const float* sparse_xyz  = (const float*)d_in[1];
    const float* sparse_flow = (const float*)d_in[2];
    float* out = (float*)d_out;

    const int B = in_sizes[1] / (3 * S_PTS);      // 2
    const int N = in_sizes[0] / (3 * B);          // 16384
    const int blocks_per_batch = (N + 63) / 64;   // 256

    dim3 grid(B * blocks_per_batch);
    dim3 block(256);
    upsample_flow_knn3<<<grid, block, 0, stream>>>(
        xyz, sparse_xyz, sparse_flow, out, N, blocks_per_batch);
}

// Round 9
// 88.554 us; speedup vs baseline: 1.0564x; 1.0492x over previous
//
#include <hip/hip_runtime.h>

#define S_PTS 4096   // sparse point count (fixed by problem)
#define NQ 4         // queries per lane
#define LQ 16        // lanes cooperating per query
#define QPB 64       // queries per block = 256/LQ*NQ
#define TSCAN (S_PTS / LQ)  // 256 points scanned per lane

// Value-only top-3 insert: b0<=b1<=b2, 3 ops, no compares/indices.
__device__ __forceinline__ void vins(float v, float& b0, float& b1, float& b2)
{
    const float n0 = fminf(b0, v);
    const float n1 = __builtin_amdgcn_fmed3f(b0, b1, v);
    const float n2 = __builtin_amdgcn_fmed3f(b1, b2, v);
    b0 = n0; b1 = n1; b2 = n2;
}

// Full sorted top-3 insert with index tracking (strict '<' => first-index
// wins on ties, matching jax.lax.top_k). No-op when d >= b2.
__device__ __forceinline__ void insert3(float d, int s,
    float& b0, float& b1, float& b2, int& i0, int& i1, int& i2)
{
    const bool lt0 = d < b0, lt1 = d < b1, lt2 = d < b2;
    i2 = lt1 ? i1 : (lt2 ? s : i2);   // reads old i1
    i1 = lt0 ? i0 : (lt1 ? s : i1);   // reads old i0
    i0 = lt0 ? s : i0;
    const float nb0 = fminf(b0, d);
    const float nb1 = __builtin_amdgcn_fmed3f(b0, b1, d);
    const float nb2 = __builtin_amdgcn_fmed3f(b1, b2, d);
    b0 = nb0; b1 = nb1; b2 = nb2;
}

// Finalize one query: weights from direct-diff norm (matches reference),
// gather flow, write 3 channels. Identical math to the passing kernels.
__device__ __forceinline__ void finalize_query(
    const float4* __restrict__ spt, const float* __restrict__ fl,
    float* __restrict__ ob, int N, int n,
    float x0, float x1, float x2, int i0, int i1, int i2)
{
    const float4 p0 = spt[i0];
    const float4 p1 = spt[i1];
    const float4 p2 = spt[i2];

    float dx, dy, dz;
    dx = p0.x - x0; dy = p0.y - x1; dz = p0.z - x2;
    const float dist0 = fmaxf(sqrtf(dx * dx + dy * dy + dz * dz), 1e-10f);
    dx = p1.x - x0; dy = p1.y - x1; dz = p1.z - x2;
    const float dist1 = fmaxf(sqrtf(dx * dx + dy * dy + dz * dz), 1e-10f);
    dx = p2.x - x0; dy = p2.y - x1; dz = p2.z - x2;
    const float dist2 = fmaxf(sqrtf(dx * dx + dy * dy + dz * dz), 1e-10f);

    const float inv0 = 1.0f / dist0;
    const float inv1 = 1.0f / dist1;
    const float inv2 = 1.0f / dist2;
    const float wsum = (inv0 + inv1) + inv2;
    const float w0 = inv0 / wsum;
    const float w1 = inv1 / wsum;
    const float w2 = inv2 / wsum;

    #pragma unroll
    for (int c = 0; c < 3; ++c) {
        const float f0 = fl[c * S_PTS + i0];
        const float f1 = fl[c * S_PTS + i1];
        const float f2 = fl[c * S_PTS + i2];
        ob[c * N + n] = (w0 * f0 + w1 * f1) + w2 * f2;
    }
}

// 256 threads = 16 groups x 16 lanes; each lane owns NQ=4 queries.
// 64 queries/block. LDS = 64 KB -> 2 blocks/CU (8 waves/CU).
__global__ __launch_bounds__(256, 2)
void upsample_flow_knn3(const float* __restrict__ xyz,         // [B,3,N]
                        const float* __restrict__ sparse_xyz,  // [B,3,S]
                        const float* __restrict__ sparse_flow, // [B,3,S]
                        float* __restrict__ out,               // [B,3,N]
                        int N, int blocks_per_batch)
{
    __shared__ float4 spt[S_PTS];  // (x, y, z, |s|^2)

    const int tid = threadIdx.x;
    const int b   = blockIdx.x / blocks_per_batch;
    const int qb  = blockIdx.x % blocks_per_batch;

    // ---- stage sparse points (+ pinned-rounded squared norm) into LDS ----
    const float* sx = sparse_xyz + (size_t)b * 3 * S_PTS;
    for (int i = tid; i < S_PTS; i += 256) {
        const float px = sx[i];
        const float py = sx[S_PTS + i];
        const float pz = sx[2 * S_PTS + i];
        const float sn = __fadd_rn(
            __fadd_rn(__fmul_rn(px, px), __fmul_rn(py, py)),
            __fmul_rn(pz, pz));
        spt[i] = make_float4(px, py, pz, sn);
    }
    __syncthreads();

    const int g = tid >> 4;   // query group (0..15)
    const int j = tid & 15;   // scanner lane within group (0..15)
    const int nbase = qb * QPB + g;   // query q of this lane: nbase + q*16

    const float* xq = xyz + (size_t)b * 3 * N;
    float x0[NQ], x1[NQ], x2[NQ], qn[NQ];
    #pragma unroll
    for (int q = 0; q < NQ; ++q) {
        const int n = nbase + q * 16;
        x0[q] = xq[n];
        x1[q] = xq[N + n];
        x2[q] = xq[2 * N + n];
        qn[q] = __fadd_rn(
            __fadd_rn(__fmul_rn(x0[q], x0[q]), __fmul_rn(x1[q], x1[q])),
            __fmul_rn(x2[q], x2[q]));
    }

    // ================= phase 1: value-only bound scan (FMA ok) ============
    // Track top-3 of e' = sn - 2*dot  (qn omitted: constant per query,
    // doesn't change within-query ordering; only a BOUND is needed).
    float v0[NQ], v1[NQ], v2[NQ];
    #pragma unroll
    for (int q = 0; q < NQ; ++q) { v0[q] = 3.4e38f; v1[q] = 3.4e38f; v2[q] = 3.4e38f; }

    #pragma unroll 4
    for (int i = 0; i < TSCAN; ++i) {
        const float4 p = spt[(i << 4) | j];
        #pragma unroll
        for (int q = 0; q < NQ; ++q) {
            const float dot = fmaf(x2[q], p.z, fmaf(x1[q], p.y, x0[q] * p.x));
            const float e   = fmaf(-2.0f, dot, p.w);
            vins(e, v0[q], v1[q], v2[q]);
        }
    }

    // merge bound values across the 16 lanes of the group
    #pragma unroll
    for (int m = 1; m <= 8; m <<= 1) {
        #pragma unroll
        for (int q = 0; q < NQ; ++q) {
            const float o0 = __shfl_xor(v0[q], m, 64);
            const float o1 = __shfl_xor(v1[q], m, 64);
            const float o2 = __shfl_xor(v2[q], m, 64);
            vins(o0, v0[q], v1[q], v2[q]);
            vins(o1, v0[q], v1[q], v2[q]);
            vins(o2, v0[q], v1[q], v2[q]);
        }
    }

    // slackened bound: covers |fma-form - pinned-form| (~3e-5) with margin
    float bnd[NQ];
    #pragma unroll
    for (int q = 0; q < NQ; ++q)
        bnd[q] = v2[q] + (2e-4f + 1e-5f * fabsf(v2[q]));

    // ============ phase 3: index recovery with exact-pinned d2 ============
    float c0[NQ], c1[NQ], c2[NQ];
    int   i0[NQ], i1[NQ], i2[NQ];
    #pragma unroll
    for (int q = 0; q < NQ; ++q) {
        c0[q] = 3.4e38f; c1[q] = 3.4e38f; c2[q] = 3.4e38f;
        i0[q] = 0; i1[q] = 0; i2[q] = 0;
    }

    #pragma unroll 2
    for (int i = 0; i < TSCAN; ++i) {
        const float4 p = spt[(i << 4) | j];
        // cheap FMA screen (no qn, matches phase-1 metric)
        bool hit = false;
        #pragma unroll
        for (int q = 0; q < NQ; ++q) {
            const float dot = fmaf(x2[q], p.z, fmaf(x1[q], p.y, x0[q] * p.x));
            const float e   = fmaf(-2.0f, dot, p.w);
            hit = hit || (e <= bnd[q]);
        }
        if (hit) {
            // rare path (~17% of wave-iters): exact reference-rounded d2.
            // insert3 is a no-op for non-qualifying values; extra inserts
            // are harmless (top-3 of a superset containing the true top-3).
            const int s = (i << 4) | j;
            #pragma unroll
            for (int q = 0; q < NQ; ++q) {
                const float dote = __fadd_rn(
                    __fadd_rn(__fmul_rn(x0[q], p.x), __fmul_rn(x1[q], p.y)),
                    __fmul_rn(x2[q], p.z));
                const float d2e = __fadd_rn(
                    __fsub_rn(qn[q], __fmul_rn(2.0f, dote)), p.w);
                insert3(d2e, s, c0[q], c1[q], c2[q], i0[q], i1[q], i2[q]);
            }
        }
    }

    // merge (value,index) triples across the 16 lanes of the group
    #pragma unroll
    for (int m = 1; m <= 8; m <<= 1) {
        #pragma unroll
        for (int q = 0; q < NQ; ++q) {
            const float r0 = __shfl_xor(c0[q], m, 64);
            const float r1 = __shfl_xor(c1[q], m, 64);
            const float r2 = __shfl_xor(c2[q], m, 64);
            const int   k0 = __shfl_xor(i0[q], m, 64);
            const int   k1 = __shfl_xor(i1[q], m, 64);
            const int   k2 = __shfl_xor(i2[q], m, 64);
            insert3(r0, k0, c0[q], c1[q], c2[q], i0[q], i1[q], i2[q]);
            insert3(r1, k1, c0[q], c1[q], c2[q], i0[q], i1[q], i2[q]);
            insert3(r2, k2, c0[q], c1[q], c2[q], i0[q], i1[q], i2[q]);
        }
    }

    // ---- finalize the lane's 4 queries on lane j==0 ----
    if (j == 0) {
        const float* fl = sparse_flow + (size_t)b * 3 * S_PTS;
        float* ob = out + (size_t)b * 3 * N;
        #pragma unroll
        for (int q = 0; q < NQ; ++q) {
            const int n = nbase + q * 16;
            if (n < N)
                finalize_query(spt, fl, ob, N, n,
                               x0[q], x1[q], x2[q], i0[q], i1[q], i2[q]);
        }
    }
}

extern "C" void kernel_launch(void* const* d_in, const int* in_sizes, int n_in,
                              void* d_out, int out_size, void* d_ws, size_t ws_size,
                              hipStream_t stream)
{
    const float* xyz         = (const float*)d_in[0];
    const float* sparse_xyz  = (const float*)d_in[1];
    const float* sparse_flow = (const float*)d_in[2];
    float* out = (float*)d_out;

    const int B = in_sizes[1] / (3 * S_PTS);        // 2
    const int N = in_sizes[0] / (3 * B);            // 16384
    const int blocks_per_batch = (N + QPB - 1) / QPB;  // 256

    dim3 grid(B * blocks_per_batch);
    dim3 block(256);
    upsample_flow_knn3<<<grid, block, 0, stream>>>(
        xyz, sparse_xyz, sparse_flow, out, N, blocks_per_batch);
}

// Round 10
// 66.199 us; speedup vs baseline: 1.4131x; 1.3377x over previous
//
#include <hip/hip_runtime.h>

#define S_PTS 4096            // sparse point count (fixed by problem)
#define TILE  2048            // points staged per LDS tile (32 KB)
#define NTILE (S_PTS / TILE)  // 2
#define LQ    16              // lanes cooperating per query
#define NQ    2               // queries per lane
#define QPB   32              // queries per block = (256/LQ)*NQ

// Guarded sorted top-3 insert: caller guarantees d < b2.
// Strict '<' keeps earliest index on ties (matches jax.lax.top_k).
__device__ __forceinline__ void insert3_hit(float d, int s,
    float& b0, float& b1, float& b2, int& i0, int& i1, int& i2)
{
    const bool lt0 = d < b0, lt1 = d < b1;
    b2 = lt1 ? b1 : d;
    i2 = lt1 ? i1 : s;
    b1 = lt0 ? b0 : (lt1 ? d : b1);
    i1 = lt0 ? i0 : (lt1 ? s : i1);
    b0 = lt0 ? d : b0;
    i0 = lt0 ? s : i0;
}

// Full sorted top-3 insert (for cross-lane merge where d may be >= b2).
__device__ __forceinline__ void insert3_full(float d, int s,
    float& b0, float& b1, float& b2, int& i0, int& i1, int& i2)
{
    const bool lt0 = d < b0, lt1 = d < b1, lt2 = d < b2;
    b2 = lt1 ? b1 : (lt2 ? d : b2);
    i2 = lt1 ? i1 : (lt2 ? s : i2);
    b1 = lt0 ? b0 : (lt1 ? d : b1);
    i1 = lt0 ? i0 : (lt1 ? s : i1);
    b0 = lt0 ? d : b0;
    i0 = lt0 ? s : i0;
}

// Finalize one query reading winner coords from GLOBAL (LDS tile is gone).
// Same dist/weight math as all passing kernels.
__device__ __forceinline__ void finalize_query_g(
    const float* __restrict__ sx, const float* __restrict__ fl,
    float* __restrict__ ob, int N, int n,
    float x0, float x1, float x2, int i0, int i1, int i2)
{
    const float ax = sx[i0], ay = sx[S_PTS + i0], az = sx[2 * S_PTS + i0];
    const float bx = sx[i1], by = sx[S_PTS + i1], bz = sx[2 * S_PTS + i1];
    const float cx = sx[i2], cy = sx[S_PTS + i2], cz = sx[2 * S_PTS + i2];

    float dx, dy, dz;
    dx = ax - x0; dy = ay - x1; dz = az - x2;
    const float dist0 = fmaxf(sqrtf(dx * dx + dy * dy + dz * dz), 1e-10f);
    dx = bx - x0; dy = by - x1; dz = bz - x2;
    const float dist1 = fmaxf(sqrtf(dx * dx + dy * dy + dz * dz), 1e-10f);
    dx = cx - x0; dy = cy - x1; dz = cz - x2;
    const float dist2 = fmaxf(sqrtf(dx * dx + dy * dy + dz * dz), 1e-10f);

    const float inv0 = 1.0f / dist0;
    const float inv1 = 1.0f / dist1;
    const float inv2 = 1.0f / dist2;
    const float wsum = (inv0 + inv1) + inv2;
    const float w0 = inv0 / wsum;
    const float w1 = inv1 / wsum;
    const float w2 = inv2 / wsum;

    #pragma unroll
    for (int c = 0; c < 3; ++c) {
        const float f0 = fl[c * S_PTS + i0];
        const float f1 = fl[c * S_PTS + i1];
        const float f2 = fl[c * S_PTS + i2];
        ob[c * N + n] = (w0 * f0 + w1 * f1) + w2 * f2;
    }
}

// 256 threads = 16 groups x 16 lanes; each lane owns NQ=2 queries.
// 32 queries/block, 32 KB LDS -> 4 blocks/CU (16 waves/CU), grid 1024 blocks.
__global__ __launch_bounds__(256, 4)
void upsample_flow_knn3(const float* __restrict__ xyz,         // [B,3,N]
                        const float* __restrict__ sparse_xyz,  // [B,3,S]
                        const float* __restrict__ sparse_flow, // [B,3,S]
                        float* __restrict__ out,               // [B,3,N]
                        int N, int blocks_per_batch)
{
    __shared__ float4 spt[TILE];  // (x, y, z, |s|^2) for current tile

    const int tid = threadIdx.x;
    const int b   = blockIdx.x / blocks_per_batch;
    const int qb  = blockIdx.x % blocks_per_batch;

    const float* sx = sparse_xyz + (size_t)b * 3 * S_PTS;

    const int g = tid >> 4;   // query group (0..15)
    const int j = tid & 15;   // scanner lane within group (0..15)
    const int nA = qb * QPB + g;
    const int nB = nA + 16;

    const float* xq = xyz + (size_t)b * 3 * N;
    const float xA0 = xq[nA];
    const float xA1 = xq[N + nA];
    const float xA2 = xq[2 * N + nA];
    const float qnA = __fadd_rn(
        __fadd_rn(__fmul_rn(xA0, xA0), __fmul_rn(xA1, xA1)),
        __fmul_rn(xA2, xA2));
    const float xB0 = xq[nB];
    const float xB1 = xq[N + nB];
    const float xB2 = xq[2 * N + nB];
    const float qnB = __fadd_rn(
        __fadd_rn(__fmul_rn(xB0, xB0), __fmul_rn(xB1, xB1)),
        __fmul_rn(xB2, xB2));

    float a0 = 3.4e38f, a1 = 3.4e38f, a2 = 3.4e38f;
    int  ia0 = 0, ia1 = 0, ia2 = 0;
    float c0 = 3.4e38f, c1 = 3.4e38f, c2 = 3.4e38f;
    int  ib0 = 0, ib1 = 0, ib2 = 0;

    for (int t = 0; t < NTILE; ++t) {
        if (t) __syncthreads();  // previous tile fully consumed before overwrite

        // ---- stage tile t (+ pinned-rounded squared norm) into LDS ----
        const int sb = t * TILE;
        for (int i = tid; i < TILE; i += 256) {
            const float px = sx[sb + i];
            const float py = sx[S_PTS + sb + i];
            const float pz = sx[2 * S_PTS + sb + i];
            const float sn = __fadd_rn(
                __fadd_rn(__fmul_rn(px, px), __fmul_rn(py, py)),
                __fmul_rn(pz, pz));
            spt[i] = make_float4(px, py, pz, sn);
        }
        __syncthreads();

        // ---- scan: lane j handles sl = 16*i + j; one LDS read, 2 queries ----
        #pragma unroll 4
        for (int i = 0; i < TILE / LQ; ++i) {
            const int sl = (i << 4) | j;
            const float4 p = spt[sl];
            const int s = sb + sl;

            // expanded-form d2, pinned rounding (identical to passing kernels):
            // d2 = (qn - 2*dot) + sn,  dot = (x0*px + x1*py) + x2*pz
            const float dotA = __fadd_rn(
                __fadd_rn(__fmul_rn(xA0, p.x), __fmul_rn(xA1, p.y)),
                __fmul_rn(xA2, p.z));
            const float d2A = __fadd_rn(
                __fsub_rn(qnA, __fmul_rn(2.0f, dotA)), p.w);
            if (d2A < a2)
                insert3_hit(d2A, s, a0, a1, a2, ia0, ia1, ia2);

            const float dotB = __fadd_rn(
                __fadd_rn(__fmul_rn(xB0, p.x), __fmul_rn(xB1, p.y)),
                __fmul_rn(xB2, p.z));
            const float d2B = __fadd_rn(
                __fsub_rn(qnB, __fmul_rn(2.0f, dotB)), p.w);
            if (d2B < c2)
                insert3_hit(d2B, s, c0, c1, c2, ib0, ib1, ib2);
        }
    }

    // ---- merge the 16 partial top-3s per query (butterfly within group) ----
    #pragma unroll
    for (int m = 1; m <= 8; m <<= 1) {
        const float ra0 = __shfl_xor(a0, m, 64);
        const float ra1 = __shfl_xor(a1, m, 64);
        const float ra2 = __shfl_xor(a2, m, 64);
        const int   ka0 = __shfl_xor(ia0, m, 64);
        const int   ka1 = __shfl_xor(ia1, m, 64);
        const int   ka2 = __shfl_xor(ia2, m, 64);
        insert3_full(ra0, ka0, a0, a1, a2, ia0, ia1, ia2);
        insert3_full(ra1, ka1, a0, a1, a2, ia0, ia1, ia2);
        insert3_full(ra2, ka2, a0, a1, a2, ia0, ia1, ia2);

        const float rb0 = __shfl_xor(c0, m, 64);
        const float rb1 = __shfl_xor(c1, m, 64);
        const float rb2 = __shfl_xor(c2, m, 64);
        const int   kb0 = __shfl_xor(ib0, m, 64);
        const int   kb1 = __shfl_xor(ib1, m, 64);
        const int   kb2 = __shfl_xor(ib2, m, 64);
        insert3_full(rb0, kb0, c0, c1, c2, ib0, ib1, ib2);
        insert3_full(rb1, kb1, c0, c1, c2, ib0, ib1, ib2);
        insert3_full(rb2, kb2, c0, c1, c2, ib0, ib1, ib2);
    }

    // ---- finalize both queries on lane j==0 (coords from global/L2) ----
    if (j == 0) {
        const float* fl = sparse_flow + (size_t)b * 3 * S_PTS;
        float* ob = out + (size_t)b * 3 * N;
        if (nA < N)
            finalize_query_g(sx, fl, ob, N, nA, xA0, xA1, xA2, ia0, ia1, ia2);
        if (nB < N)
            finalize_query_g(sx, fl, ob, N, nB, xB0, xB1, xB2, ib0, ib1, ib2);
    }
}

extern "C" void kernel_launch(void* const* d_in, const int* in_sizes, int n_in,
                              void* d_out, int out_size, void* d_ws, size_t ws_size,
                              hipStream_t stream)
{
    const float* xyz         = (const float*)d_in[0];
    const float* sparse_xyz  = (const float*)d_in[1];
    const float* sparse_flow = (const float*)d_in[2];
    float* out = (float*)d_out;

    const int B = in_sizes[1] / (3 * S_PTS);          // 2
    const int N = in_sizes[0] / (3 * B);              // 16384
    const int blocks_per_batch = (N + QPB - 1) / QPB; // 512

    dim3 grid(B * blocks_per_batch);                  // 1024 blocks
    dim3 block(256);
    upsample_flow_knn3<<<grid, block, 0, stream>>>(
        xyz, sparse_xyz, sparse_flow, out, N, blocks_per_batch);
}